// Round 1
// baseline (23.856 us; speedup 1.0000x reference)
//
#include <hip/hip_runtime.h>
#include <hip/hip_bf16.h>

#define BLK 256
#define MAXJ 2            // supports K <= 2*BLK*MAXJ = 1024 classes (K=1000 here)
#define CE_T_DEV 5
#define EPS_DEV 1e-6f

__global__ void zero_kernel(float* out) { out[0] = 0.0f; }

__device__ __forceinline__ float wave_reduce_add(float v) {
#pragma unroll
  for (int o = 32; o > 0; o >>= 1) v += __shfl_down(v, o, 64);
  return v;
}

// One block per row b. Two passes over K classes, per-class data held in registers.
template <bool USE_WS>
__global__ __launch_bounds__(BLK) void loss_kernel(
    const float* __restrict__ logits,
    const int* __restrict__ labels,
    const int* __restrict__ epoch_p,
    float* __restrict__ row_out,   // USE_WS: ws[B]; else: out[0] (atomic)
    int B, int K) {
  const int b = blockIdx.x;
  const int tid = threadIdx.x;
  const int lane = tid & 63;
  const int wv = tid >> 6;
  constexpr int NW = BLK / 64;
  __shared__ float sm[4][NW];

  const int label = labels[b];
  const float* __restrict__ row = logits + (size_t)b * (size_t)(2 * K);
  const int half = K >> 1;

  float b0[2 * MAXJ], dd[2 * MAXJ];
  float acc_ign = 0.f, acc_ed = 0.f;

  // ---- pass 1: 2-way log-softmax per class, accumulate ignorance_log & sum(exp(d))
#pragma unroll
  for (int j = 0; j < MAXJ; ++j) {
    const int c = tid + j * BLK;
    if (c < half) {
      const float4 v = *reinterpret_cast<const float4*>(row + 4 * (size_t)c);
#pragma unroll
      for (int k = 0; k < 2; ++k) {
        const float l0 = k ? v.z : v.x;
        const float l1 = k ? v.w : v.y;
        const float d = l0 - l1;
        const float lse = fmaxf(l0, l1) + logf(1.f + expf(-fabsf(d)));
        acc_ign += l1 - lse;
        acc_ed += expf(d);
        b0[2 * j + k] = l0 - lse;   // beliefs_log[...,0]
        dd[2 * j + k] = d;          // bl0 - bl1
      }
    }
  }
  float tb0 = 0.f, td = 0.f;       // odd-K tail (unused for K=1000)
  if ((K & 1) && tid == 0) {
    const float l0 = row[2 * (size_t)(K - 1)];
    const float l1 = row[2 * (size_t)(K - 1) + 1];
    const float d = l0 - l1;
    const float lse = fmaxf(l0, l1) + logf(1.f + expf(-fabsf(d)));
    tb0 = l0 - lse; td = d;
    acc_ign += l1 - lse;
    acc_ed += expf(d);
  }

  {
    float ri = wave_reduce_add(acc_ign);
    float re = wave_reduce_add(acc_ed);
    if (lane == 0) { sm[0][wv] = ri; sm[1][wv] = re; }
  }
  __syncthreads();
  float ign = 0.f, sed = 0.f;
#pragma unroll
  for (int w = 0; w < NW; ++w) { ign += sm[0][w]; sed += sm[1][w]; }
  __syncthreads();

  // ---- row scalars
  const float eign = expf(ign);              // exp(ignorance_log)
  const float sum_belief = eign * sed;
  const float unc = 1.f - sum_belief;
  const float S = (float)K / (unc + EPS_DEV);
  const float S_a = S * sum_belief + (float)K;   // sum(alpha)
  const float inv_Sa = 1.f / S_a;
  const float inv_den = 1.f / (S_a * S_a * (S_a + 1.f));
  const float pmax = 1.f - eign;             // plausibility_max

  // ---- pass 2: CE + EDL terms from registers
  float a_err = 0.f, a_var = 0.f, a_ce = 0.f, a_bgt = 0.f;
#pragma unroll
  for (int j = 0; j < MAXJ; ++j) {
    const int c = tid + j * BLK;
    if (c < half) {
#pragma unroll
      for (int k = 0; k < 2; ++k) {
        const int i = 2 * c + k;
        const float bl0 = b0[2 * j + k];
        const float d = dd[2 * j + k];
        const float bl1 = bl0 - d;
        const float belief = expf(ign + d);
        const float alpha = belief * S + 1.f;
        const float p = alpha * inv_Sa;
        const bool is = (i == label);
        const float e = (is ? 1.f : 0.f) - p;
        a_err += e * e;
        a_var += alpha * (S_a - alpha);
        a_ce += is ? -bl0 : -bl1;
        if (is) a_bgt = expf(bl0);
      }
    }
  }
  if ((K & 1) && tid == 0) {
    const int i = K - 1;
    const float bl1 = tb0 - td;
    const float belief = expf(ign + td);
    const float alpha = belief * S + 1.f;
    const float p = alpha * inv_Sa;
    const bool is = (i == label);
    const float e = (is ? 1.f : 0.f) - p;
    a_err += e * e;
    a_var += alpha * (S_a - alpha);
    a_ce += is ? -tb0 : -bl1;
    if (is) a_bgt = expf(tb0);
  }

  a_err = wave_reduce_add(a_err);
  a_var = wave_reduce_add(a_var);
  a_ce  = wave_reduce_add(a_ce);
  a_bgt = wave_reduce_add(a_bgt);
  if (lane == 0) { sm[0][wv] = a_err; sm[1][wv] = a_var; sm[2][wv] = a_ce; sm[3][wv] = a_bgt; }
  __syncthreads();
  if (tid == 0) {
    float terr = 0.f, tvar = 0.f, tce = 0.f, tbgt = 0.f;
#pragma unroll
    for (int w = 0; w < NW; ++w) { terr += sm[0][w]; tvar += sm[1][w]; tce += sm[2][w]; tbgt += sm[3][w]; }
    const float edl1 = terr + tvar * inv_den;
    const float bd = tbgt - pmax;
    const float edl2 = bd * bd;
    float contrib = (edl1 + edl2) / (float)B;
    if (epoch_p[0] < CE_T_DEV) contrib += tce / ((float)B * (float)K);
    if (USE_WS) row_out[b] = contrib;
    else        atomicAdd(row_out, contrib);
  }
}

__global__ __launch_bounds__(256) void reduce_kernel(const float* __restrict__ ws,
                                                     float* __restrict__ out, int B) {
  const int tid = threadIdx.x;
  const int lane = tid & 63;
  const int wv = tid >> 6;
  __shared__ float sm[4];
  float acc = 0.f;
  for (int i = tid; i < B; i += 256) acc += ws[i];
  acc = wave_reduce_add(acc);
  if (lane == 0) sm[wv] = acc;
  __syncthreads();
  if (tid == 0) out[0] = sm[0] + sm[1] + sm[2] + sm[3];
}

extern "C" void kernel_launch(void* const* d_in, const int* in_sizes, int n_in,
                              void* d_out, int out_size, void* d_ws, size_t ws_size,
                              hipStream_t stream) {
  const float* logits = (const float*)d_in[0];
  const int* labels = (const int*)d_in[1];
  const int* epoch = (const int*)d_in[2];
  float* out = (float*)d_out;

  const int B = in_sizes[1];
  const int K = in_sizes[0] / (2 * B);

  if (ws_size >= (size_t)B * sizeof(float)) {
    float* ws = (float*)d_ws;
    loss_kernel<true><<<B, BLK, 0, stream>>>(logits, labels, epoch, ws, B, K);
    reduce_kernel<<<1, 256, 0, stream>>>(ws, out, B);
  } else {
    zero_kernel<<<1, 64, 0, stream>>>(out);
    loss_kernel<false><<<B, BLK, 0, stream>>>(logits, labels, epoch, out, B, K);
  }
}

// Round 2
// 17.764 us; speedup vs baseline: 1.3430x; 1.3430x over previous
//
#include <hip/hip_runtime.h>
#include <hip/hip_bf16.h>

#define CE_T_DEV 5
#define EPS_DEV 1e-6f

__global__ void zero_kernel(float* out) { out[0] = 0.0f; }

// butterfly: every lane ends with the full 64-lane sum
__device__ __forceinline__ float wave_bcast_sum(float v) {
#pragma unroll
  for (int m = 1; m < 64; m <<= 1) v += __shfl_xor(v, m, 64);
  return v;
}

// One WAVE per row. Single pass over K classes accumulating 5 scalars:
//   ign = sum(bl1), sed = sum(e^d), sq2 = sum(e^2d), c_ed = e^d @label, c_bl1 = bl1 @label
// Everything else is closed-form per row (see launch-file header derivation):
//   S_a   = eign*S*sed + K
//   sa2   = (S*eign)^2*sq2 + 2*S*eign*sed + K          (= sum alpha^2)
//   err   = sa2/S_a^2 - 2*alpha_lab/S_a + 1
//   var   = (S_a^2 - sa2) / (S_a^2 (S_a+1))
//   ce    = -(ign + d_lab),  d_lab = log(c_ed)
//   bgt   = exp(c_bl1 + d_lab)
template <bool USE_WS>
__global__ __launch_bounds__(256) void loss_kernel(
    const float* __restrict__ logits,
    const int* __restrict__ labels,
    const int* __restrict__ epoch_p,
    float* __restrict__ row_out,   // USE_WS: ws[B]; else out[0] via atomic
    int B, int K) {
  const int tid = threadIdx.x;
  const int lane = tid & 63;
  const int wv = tid >> 6;
  const int row = blockIdx.x * 4 + wv;
  if (row >= B) return;

  const int label = labels[row];
  const float* __restrict__ rp = logits + (size_t)row * (size_t)(2 * K);
  const int pairs = K >> 1;

  float ign = 0.f, sed = 0.f, sq2 = 0.f, c_ed = 0.f, c_bl1 = 0.f;

  for (int p = lane; p < pairs; p += 64) {
    const float4 v = *reinterpret_cast<const float4*>(rp + 4 * (size_t)p);
#pragma unroll
    for (int k = 0; k < 2; ++k) {
      const float l0 = k ? v.z : v.x;
      const float l1 = k ? v.w : v.y;
      const float d = l0 - l1;
      const float em = __expf(-fabsf(d));
      const float lse = fmaxf(l0, l1) + __logf(1.f + em);
      const float bl1 = l1 - lse;
      const float ed = __expf(d);
      ign += bl1;
      sed += ed;
      sq2 = fmaf(ed, ed, sq2);
      const bool is = (2 * p + k == label);
      c_ed = is ? ed : c_ed;
      c_bl1 = is ? bl1 : c_bl1;
    }
  }
  if ((K & 1) && lane == 0) {            // odd-K tail (unused for K=1000)
    const int i = K - 1;
    const float l0 = rp[2 * (size_t)i];
    const float l1 = rp[2 * (size_t)i + 1];
    const float d = l0 - l1;
    const float em = __expf(-fabsf(d));
    const float lse = fmaxf(l0, l1) + __logf(1.f + em);
    const float bl1 = l1 - lse;
    const float ed = __expf(d);
    ign += bl1; sed += ed; sq2 = fmaf(ed, ed, sq2);
    if (i == label) { c_ed = ed; c_bl1 = bl1; }
  }

  ign  = wave_bcast_sum(ign);
  sed  = wave_bcast_sum(sed);
  sq2  = wave_bcast_sum(sq2);
  c_ed = wave_bcast_sum(c_ed);    // only owning lane nonzero -> sum == value
  c_bl1 = wave_bcast_sum(c_bl1);

  if (lane == 0) {
    const float eign = __expf(ign);                 // exp(ignorance_log)
    const float sb = eign * sed;                    // sum(belief)
    const float S = (float)K / ((1.f - sb) + EPS_DEV);
    const float Se = S * eign;
    const float S_a = Se * sed + (float)K;          // sum(alpha)
    const float inv_Sa = 1.f / S_a;
    const float sa2 = Se * Se * sq2 + 2.f * Se * sed + (float)K;  // sum(alpha^2)
    const float alpha_lab = Se * c_ed + 1.f;
    const float err = sa2 * inv_Sa * inv_Sa - 2.f * alpha_lab * inv_Sa + 1.f;
    const float var = (S_a * S_a - sa2) / (S_a * S_a * (S_a + 1.f));
    const float d_lab = __logf(c_ed);
    const float bgt = __expf(c_bl1 + d_lab);        // plausibility @ label
    const float pmax = 1.f - eign;
    const float edl2 = (bgt - pmax) * (bgt - pmax);
    float contrib = (err + var + edl2) / (float)B;
    if (epoch_p[0] < CE_T_DEV) contrib += -(ign + d_lab) / ((float)B * (float)K);
    if (USE_WS) row_out[row] = contrib;
    else        atomicAdd(row_out, contrib);
  }
}

__global__ __launch_bounds__(256) void reduce_kernel(const float* __restrict__ ws,
                                                     float* __restrict__ out, int B) {
  const int tid = threadIdx.x;
  const int lane = tid & 63;
  const int wv = tid >> 6;
  __shared__ float sm[4];
  float acc = 0.f;
  for (int i = tid; i < B; i += 256) acc += ws[i];
  acc = wave_bcast_sum(acc);
  if (lane == 0) sm[wv] = acc;
  __syncthreads();
  if (tid == 0) out[0] = sm[0] + sm[1] + sm[2] + sm[3];
}

extern "C" void kernel_launch(void* const* d_in, const int* in_sizes, int n_in,
                              void* d_out, int out_size, void* d_ws, size_t ws_size,
                              hipStream_t stream) {
  const float* logits = (const float*)d_in[0];
  const int* labels = (const int*)d_in[1];
  const int* epoch = (const int*)d_in[2];
  float* out = (float*)d_out;

  const int B = in_sizes[1];
  const int K = in_sizes[0] / (2 * B);
  const int grid = (B + 3) / 4;

  if (ws_size >= (size_t)B * sizeof(float)) {
    float* ws = (float*)d_ws;
    loss_kernel<true><<<grid, 256, 0, stream>>>(logits, labels, epoch, ws, B, K);
    reduce_kernel<<<1, 256, 0, stream>>>(ws, out, B);
  } else {
    zero_kernel<<<1, 64, 0, stream>>>(out);
    loss_kernel<false><<<grid, 256, 0, stream>>>(logits, labels, epoch, out, B, K);
  }
}